// Round 2
// baseline (298.632 us; speedup 1.0000x reference)
//
#include <hip/hip_runtime.h>

#define NB   128
#define NN   32
#define OBS  64
#define ACTD 16
#define DD   80     // OBS + ACT
#define HID  64
#define FIN  128    // OBS + ZOUT

// one layer: O[j][h] = act(b[h] + sum_k X[j*K+k] * W[k*64+h])
// 256 threads: h = t&63 (64 output cols), jg = t>>6; rows j = jg + 4*i, i=0..7
template<int K>
__device__ __forceinline__ void layer256(const float* X, const float* __restrict__ W,
                                         const float* __restrict__ bias, float* O,
                                         int h, int jg, bool act)
{
    float acc[8];
    const float bv = bias[h];
#pragma unroll
    for (int i = 0; i < 8; ++i) acc[i] = bv;
    for (int k = 0; k < K; ++k) {
        const float w = W[k * 64 + h];
#pragma unroll
        for (int i = 0; i < 8; ++i)
            acc[i] = fmaf(X[(jg + 4 * i) * K + k], w, acc[i]);
    }
#pragma unroll
    for (int i = 0; i < 8; ++i) {
        float v = acc[i];
        if (act) v = v >= 0.f ? v : 0.01f * v;
        O[(jg + 4 * i) * 64 + h] = v;
    }
}

// ---------------- kernel 1: per-batch setup ----------------
// computes weight_z (output 2 slot), key_obsz -> ws, vals_pi -> ws
__global__ __launch_bounds__(256)
void setup_kernel(const float* __restrict__ states,    // B,N,64
                  const float* __restrict__ policies,  // B,N,16
                  const float* __restrict__ actions,   // B,N,16
                  const float* __restrict__ kw1_w, const float* __restrict__ kw1_b,
                  const float* __restrict__ kw2_w, const float* __restrict__ kw2_b,
                  const float* __restrict__ qw1_w, const float* __restrict__ qw1_b,
                  const float* __restrict__ qw2_w, const float* __restrict__ qw2_b,
                  const float* __restrict__ ko1_w, const float* __restrict__ ko1_b,
                  const float* __restrict__ ko2_w, const float* __restrict__ ko2_b,
                  const float* __restrict__ av1_w, const float* __restrict__ av1_b,
                  const float* __restrict__ av2_w, const float* __restrict__ av2_b,
                  float* __restrict__ out_wz,          // B,N,N
                  float* __restrict__ ws_kobs,         // B,N,64
                  float* __restrict__ ws_vpi)          // B,N,64
{
    const int b  = blockIdx.x;
    const int t  = threadIdx.x;
    const int h  = t & 63;
    const int jg = t >> 6;

    __shared__ float s_st[NN * OBS];    // states[b]
    __shared__ float s_h[NN * HID];     // hidden scratch
    __shared__ float s_kz[NN * HID];
    __shared__ float s_qz[NN * HID];
    __shared__ float s_wz[NN * NN];     // weight_z [a][j]
    __shared__ float s_src[NN * DD];    // 32 x 80

    for (int i = t; i < NN * OBS; i += 256) s_st[i] = states[b * NN * OBS + i];
    __syncthreads();

    // key_z = mlp(states, kw)
    layer256<64>(s_st, kw1_w, kw1_b, s_h, h, jg, true);   __syncthreads();
    layer256<64>(s_h, kw2_w, kw2_b, s_kz, h, jg, false);  __syncthreads();
    // query_z = mlp(states, qw)
    layer256<64>(s_st, qw1_w, qw1_b, s_h, h, jg, true);   __syncthreads();
    layer256<64>(s_h, qw2_w, qw2_b, s_qz, h, jg, false);  __syncthreads();

    // scores_z[a][j] = dot(kz[a], qz[j]);  weight_z = sigmoid(s/8)
#pragma unroll
    for (int r = 0; r < 4; ++r) {
        const int idx = t + 256 * r;
        const int a_ = idx >> 5, j = idx & 31;
        float acc = 0.f;
        for (int k = 0; k < 64; ++k)
            acc = fmaf(s_kz[a_ * 64 + k], s_qz[j * 64 + k], acc);
        const float w = 1.f / (1.f + __expf(-acc * 0.125f));
        s_wz[idx] = w;
        out_wz[b * NN * NN + idx] = w;
    }
    __syncthreads();

    // source rows: [states[a], z[a,a]]   (diag: a==j, so states[b,a] is correct)
    for (int i = t; i < NN * DD; i += 256) {
        const int a_ = i / DD, k = i % DD;
        float v;
        if (k < OBS) v = s_st[a_ * OBS + k];
        else {
            const float w = s_wz[a_ * NN + a_];
            const int c = k - OBS;
            v = w * actions[b * NN * ACTD + a_ * ACTD + c] +
                (1.f - w) * policies[b * NN * ACTD + a_ * ACTD + c];
        }
        s_src[i] = v;
    }
    __syncthreads();

    // key_obsz = mlp(source, ko) -> ws
    layer256<80>(s_src, ko1_w, ko1_b, s_h, h, jg, true);  __syncthreads();
    layer256<64>(s_h, ko2_w, ko2_b, s_kz, h, jg, false);  __syncthreads();
    for (int i = t; i < NN * HID; i += 256) ws_kobs[b * NN * HID + i] = s_kz[i];

    // sp rows: [states[a], policies[a]]
    for (int i = t; i < NN * DD; i += 256) {
        const int a_ = i / DD, k = i % DD;
        s_src[i] = (k < OBS) ? s_st[a_ * OBS + k]
                             : policies[b * NN * ACTD + a_ * ACTD + (k - OBS)];
    }
    __syncthreads();

    // vals_pi = mlp(sp, av) -> ws
    layer256<80>(s_src, av1_w, av1_b, s_h, h, jg, true);  __syncthreads();
    layer256<64>(s_h, av2_w, av2_b, s_qz, h, jg, false);  __syncthreads();
    for (int i = t; i < NN * HID; i += 256) ws_vpi[b * NN * HID + i] = s_qz[i];
}

// ---------------- kernel 2: per-(b,a) main ----------------
__global__ __launch_bounds__(256)
void main_kernel(const float* __restrict__ states,
                 const float* __restrict__ policies,
                 const float* __restrict__ actions,
                 const float* __restrict__ qo1_w, const float* __restrict__ qo1_b,
                 const float* __restrict__ qo2_w, const float* __restrict__ qo2_b,
                 const float* __restrict__ av1_w, const float* __restrict__ av1_b,
                 const float* __restrict__ av2_w, const float* __restrict__ av2_b,
                 const float* __restrict__ fv1_w, const float* __restrict__ fv1_b,
                 const float* __restrict__ fv2_w, const float* __restrict__ fv2_b,
                 const float* __restrict__ wz,     // B,N,N (from d_out)
                 const float* __restrict__ kobs,   // B,N,64
                 const float* __restrict__ vpi,    // B,N,64
                 float* __restrict__ out_value,    // B,N,N
                 float* __restrict__ out_wobs)     // B,N,N
{
    const int blk = blockIdx.x;
    const int b = blk >> 5, a = blk & 31;
    const int t = threadIdx.x, h = t & 63, jg = t >> 6;

    __shared__ float s_states[NN * OBS];   // states[b] (all 32 rows — obs_z/node_in use row j!)
    __shared__ float s_ko[HID];            // key_obsz[b,a]
    __shared__ float s_wzr[NN];            // weight_z[b,a,:]
    __shared__ float s_ap[NN * ACTD * 2];  // actions[b] then policies[b]
    __shared__ float s_vpi[NN * HID];
    __shared__ float s_X[NN * FIN];        // obs_z (80-wide) then node_in (128-wide)
    __shared__ float s_h1[NN * HID];
    __shared__ float s_q[NN * HID];        // Q then VALS
    __shared__ float s_sc[NN];
    __shared__ float s_w[NN];
    __shared__ float s_sum[HID];

    for (int i = t; i < NN * OBS; i += 256) s_states[i] = states[b * NN * OBS + i];
    if (t < 64)        s_ko[t]        = kobs[(b * NN + a) * HID + t];
    else if (t < 96)   s_wzr[t - 64]  = wz[b * NN * NN + a * NN + (t - 64)];
    for (int i = t; i < NN * ACTD; i += 256) {
        s_ap[i]             = actions[b * NN * ACTD + i];
        s_ap[NN * ACTD + i] = policies[b * NN * ACTD + i];
    }
    for (int i = t; i < NN * HID; i += 256) s_vpi[i] = vpi[b * NN * HID + i];
    __syncthreads();

    // obs_z rows (width 80): [states[b,j], z[b,a,j]]
    for (int i = t; i < NN * DD; i += 256) {
        const int j = i / DD, k = i % DD;
        float v;
        if (k < OBS) v = s_states[j * OBS + k];
        else {
            const float w = s_wzr[j];
            const int c = k - OBS;
            v = w * s_ap[j * ACTD + c] + (1.f - w) * s_ap[NN * ACTD + j * ACTD + c];
        }
        s_X[i] = v;
    }
    __syncthreads();

    // Q = mlp(obs_z, qo)
    layer256<80>(s_X, qo1_w, qo1_b, s_h1, h, jg, true);   __syncthreads();
    layer256<64>(s_h1, qo2_w, qo2_b, s_q, h, jg, false);  __syncthreads();

    // scores[j] = dot(key_obsz[b,a], Q[j]) / 8
    if (t < NN) {
        float acc = 0.f;
        for (int k = 0; k < HID; ++k) acc = fmaf(s_ko[k], s_q[t * HID + k], acc);
        s_sc[t] = acc * 0.125f;
    }
    __syncthreads();

    // softmax over j (redundant per-thread; 32 elems)
    {
        float m = -1e30f;
        for (int j = 0; j < NN; ++j) m = fmaxf(m, s_sc[j]);
        float sum = 0.f;
        for (int j = 0; j < NN; ++j) sum += __expf(s_sc[j] - m);
        if (t < NN) {
            const float w = __expf(s_sc[t] - m) / sum;
            s_w[t] = w;
            out_wobs[b * NN * NN + a * NN + t] = w;
        }
    }
    __syncthreads();

    // VALS = mlp(obs_z, av) -> s_q (Q no longer needed)
    layer256<80>(s_X, av1_w, av1_b, s_h1, h, jg, true);   __syncthreads();
    layer256<64>(s_h1, av2_w, av2_b, s_q, h, jg, false);  __syncthreads();

    // sum_all[d] = sum_j w[j]*vals[j][d]
    if (t < HID) {
        float acc = 0.f;
        for (int j = 0; j < NN; ++j) acc = fmaf(s_w[j], s_q[j * HID + t], acc);
        s_sum[t] = acc;
    }
    __syncthreads();

    // node_in rows (width 128): [states[b,j], node_features[b,a,j]]
    for (int i = t; i < NN * FIN; i += 256) {
        const int j = i >> 7, k = i & 127;
        float v;
        if (k < OBS) v = s_states[j * OBS + k];
        else {
            const int d = k - OBS;
            const float w = s_w[j];
            v = (s_sum[d] - w * s_q[j * HID + d] + w * s_vpi[j * HID + d]) * (1.f / 32.f);
        }
        s_X[i] = v;
    }
    __syncthreads();

    // F1 = leaky(node_in @ fv1 + b)
    layer256<128>(s_X, fv1_w, fv1_b, s_h1, h, jg, true);  __syncthreads();

    // value[j] = dot(F1[j], fv2) + fb2
    if (t < NN) {
        float acc = fv2_b[0];
        for (int k = 0; k < HID; ++k) acc = fmaf(s_h1[t * HID + k], fv2_w[k], acc);
        out_value[b * NN * NN + a * NN + t] = acc;
    }
}

extern "C" void kernel_launch(void* const* d_in, const int* in_sizes, int n_in,
                              void* d_out, int out_size, void* d_ws, size_t ws_size,
                              hipStream_t stream)
{
    const float* states   = (const float*)d_in[0];
    const float* policies = (const float*)d_in[1];
    const float* actions  = (const float*)d_in[2];
    const float* kw1_w = (const float*)d_in[3];  const float* kw1_b = (const float*)d_in[4];
    const float* kw2_w = (const float*)d_in[5];  const float* kw2_b = (const float*)d_in[6];
    const float* qw1_w = (const float*)d_in[7];  const float* qw1_b = (const float*)d_in[8];
    const float* qw2_w = (const float*)d_in[9];  const float* qw2_b = (const float*)d_in[10];
    const float* ko1_w = (const float*)d_in[11]; const float* ko1_b = (const float*)d_in[12];
    const float* ko2_w = (const float*)d_in[13]; const float* ko2_b = (const float*)d_in[14];
    const float* qo1_w = (const float*)d_in[15]; const float* qo1_b = (const float*)d_in[16];
    const float* qo2_w = (const float*)d_in[17]; const float* qo2_b = (const float*)d_in[18];
    const float* av1_w = (const float*)d_in[19]; const float* av1_b = (const float*)d_in[20];
    const float* av2_w = (const float*)d_in[21]; const float* av2_b = (const float*)d_in[22];
    const float* fv1_w = (const float*)d_in[23]; const float* fv1_b = (const float*)d_in[24];
    const float* fv2_w = (const float*)d_in[25]; const float* fv2_b = (const float*)d_in[26];

    float* out   = (float*)d_out;
    float* out_value = out;                 // B*N*N = 131072
    float* out_wz    = out + 131072;        // B*N*N
    float* out_wobs  = out + 262144;        // B*N*N

    float* ws_kobs = (float*)d_ws;          // B*N*64 = 262144 floats
    float* ws_vpi  = ws_kobs + 262144;      // B*N*64

    setup_kernel<<<NB, 256, 0, stream>>>(
        states, policies, actions,
        kw1_w, kw1_b, kw2_w, kw2_b,
        qw1_w, qw1_b, qw2_w, qw2_b,
        ko1_w, ko1_b, ko2_w, ko2_b,
        av1_w, av1_b, av2_w, av2_b,
        out_wz, ws_kobs, ws_vpi);

    main_kernel<<<NB * NN, 256, 0, stream>>>(
        states, policies, actions,
        qo1_w, qo1_b, qo2_w, qo2_b,
        av1_w, av1_b, av2_w, av2_b,
        fv1_w, fv1_b, fv2_w, fv2_b,
        out_wz, ws_kobs, ws_vpi,
        out_value, out_wobs);
}

// Round 4
// 114.154 us; speedup vs baseline: 2.6161x; 2.6161x over previous
//
#include <hip/hip_runtime.h>

#define NB   128
#define NN   32
#define OBS  64
#define ACTD 16
#define HID  64

// O[j*64+h] = (ACT?leaky:id)( bias[h] + sum_k X[j*K+k]*W[k*64+h] )
// X in LDS (wave-broadcast reads), W global (K x 64 row-major), 32 rows, 256 thr
template<int K, bool ACT>
__device__ __forceinline__ void layer256(const float* X, const float* __restrict__ W,
                                         const float* __restrict__ bias, float* O,
                                         int h, int jg)
{
    float acc[8];
    const float bv = bias ? bias[h] : 0.f;
#pragma unroll
    for (int i = 0; i < 8; ++i) acc[i] = bv;
    for (int k = 0; k < K; ++k) {
        const float w = W[k * 64 + h];
#pragma unroll
        for (int i = 0; i < 8; ++i)
            acc[i] = fmaf(X[(jg + 4 * i) * K + k], w, acc[i]);
    }
#pragma unroll
    for (int i = 0; i < 8; ++i) {
        float v = acc[i];
        if (ACT) v = v >= 0.f ? v : 0.01f * v;
        O[(jg + 4 * i) * 64 + h] = v;
    }
}

// ---------------- kernel 0: M = av2_w @ fv1b, c = av2_b @ fv1b ----------------
__global__ __launch_bounds__(256)
void mm64_kernel(const float* __restrict__ av2_w, const float* __restrict__ av2_b,
                 const float* __restrict__ fv1_w,   // 128x64; rows 64..127 = fv1b
                 float* __restrict__ M, float* __restrict__ c)
{
    const int t = threadIdx.x, h = t & 63, jg = t >> 6;
    __shared__ float sA[64 * 64];
    for (int i = t; i < 4096; i += 256) sA[i] = av2_w[i];
    __syncthreads();
    const float* W = fv1_w + 64 * 64;
    float acc[16];
#pragma unroll
    for (int i = 0; i < 16; ++i) acc[i] = 0.f;
    for (int m = 0; m < 64; ++m) {
        const float w = W[m * 64 + h];
#pragma unroll
        for (int i = 0; i < 16; ++i)
            acc[i] = fmaf(sA[(jg + 4 * i) * 64 + m], w, acc[i]);
    }
#pragma unroll
    for (int i = 0; i < 16; ++i) M[(jg + 4 * i) * 64 + h] = acc[i];
    if (t < 64) {
        float s = 0.f;
        for (int m = 0; m < 64; ++m) s = fmaf(av2_b[m], W[m * 64 + t], s);
        c[t] = s;
    }
}

// ---------------- kernel 1: per-b setup ----------------
__global__ __launch_bounds__(256)
void setup_kernel(const float* __restrict__ states,    // B,N,64
                  const float* __restrict__ policies,  // B,N,16
                  const float* __restrict__ actions,   // B,N,16
                  const float* __restrict__ kw1_w, const float* __restrict__ kw1_b,
                  const float* __restrict__ kw2_w, const float* __restrict__ kw2_b,
                  const float* __restrict__ qw1_w, const float* __restrict__ qw1_b,
                  const float* __restrict__ qw2_w, const float* __restrict__ qw2_b,
                  const float* __restrict__ ko1_w, const float* __restrict__ ko1_b,
                  const float* __restrict__ ko2_w, const float* __restrict__ ko2_b,
                  const float* __restrict__ qo1_w, const float* __restrict__ qo1_b,
                  const float* __restrict__ qo2_w, const float* __restrict__ qo2_b,
                  const float* __restrict__ av1_w, const float* __restrict__ av1_b,
                  const float* __restrict__ fv1_w, const float* __restrict__ fv1_b,
                  const float* __restrict__ M, const float* __restrict__ c,
                  float* __restrict__ out_wz,          // B,N,N (d_out slot 1)
                  float* __restrict__ kq,              // B,N,64  (scaled 0.125)
                  float* __restrict__ kb,              // B,N     (scaled 0.125)
                  float* __restrict__ baseq,           // B,N,64
                  float* __restrict__ deltaq,          // B,N,64
                  float* __restrict__ basev,           // B,N,64
                  float* __restrict__ deltav,          // B,N,64
                  float* __restrict__ pre,             // B,N,64
                  float* __restrict__ vpf)             // B,N,64
{
    const int b = blockIdx.x, t = threadIdx.x, h = t & 63, jg = t >> 6;

    __shared__ float ST[NN * OBS];     // 2048
    __shared__ float AP[NN * ACTD * 2];// 1024 (act | pol)
    __shared__ float H[NN * HID];      // 2048 scratch
    __shared__ float P[6144];          // phase-overlaid pool
    __shared__ float WZD[NN];          // diag of weight_z

    for (int i = t; i < 2048; i += 256) ST[i] = states[b * 2048 + i];
    for (int i = t; i < 512; i += 256) {
        AP[i]       = actions [b * 512 + i];
        AP[512 + i] = policies[b * 512 + i];
    }
    __syncthreads();

    // ---- weight_z ----
    float* KZ = P; float* QZ = P + 2048;
    layer256<64, true >(ST, kw1_w, kw1_b, H,  h, jg); __syncthreads();
    layer256<64, false>(H,  kw2_w, kw2_b, KZ, h, jg); __syncthreads();
    layer256<64, true >(ST, qw1_w, qw1_b, H,  h, jg); __syncthreads();
    layer256<64, false>(H,  qw2_w, qw2_b, QZ, h, jg); __syncthreads();

#pragma unroll
    for (int r = 0; r < 4; ++r) {
        const int idx = t + 256 * r, a_ = idx >> 5, j = idx & 31;
        float acc = 0.f;
        for (int k = 0; k < 64; ++k) acc = fmaf(KZ[a_ * 64 + k], QZ[j * 64 + k], acc);
        const float w = 1.f / (1.f + __expf(-acc * 0.125f));
        out_wz[b * 1024 + idx] = w;
        if (a_ == j) WZD[a_] = w;
    }
    __syncthreads();

    // ---- key_obsz (diag source) ----
    float* SRC = P;                 // 32x80 (KZ/QZ dead)
    for (int i = t; i < 2560; i += 256) {
        const int a_ = i / 80, k = i % 80;
        float v;
        if (k < 64) v = ST[a_ * 64 + k];
        else {
            const float w = WZD[a_]; const int cc = k - 64;
            v = w * AP[a_ * 16 + cc] + (1.f - w) * AP[512 + a_ * 16 + cc];
        }
        SRC[i] = v;
    }
    __syncthreads();
    float* KOBS = P + 4096;
    layer256<80, true >(SRC, ko1_w, ko1_b, H,    h, jg); __syncthreads();
    layer256<64, false>(H,   ko2_w, ko2_b, KOBS, h, jg); __syncthreads();

    // ---- kq[a][h] = 0.125 * sum_d qo2_w[h][d]*kobs[a][d] ; kb = 0.125 * qo2_b . kobs ----
    // stage qo2_w row-major with per-row xor swizzle: T[h][d ^ (h&31)] = qo2_w[h][d]
    float* T = P;                   // 64x64 (SRC dead after KOBS built)
    for (int i = t; i < 4096; i += 256) {
        const int hh = i >> 6, d = i & 63;
        T[hh * 64 + (d ^ (hh & 31))] = qo2_w[i];
    }
    __syncthreads();
    {
        float acc[8];
#pragma unroll
        for (int i = 0; i < 8; ++i) acc[i] = 0.f;
        for (int d = 0; d < 64; ++d) {
            const float tv = T[h * 64 + (d ^ (h & 31))];   // = qo2_w[h][d]
#pragma unroll
            for (int i = 0; i < 8; ++i)
                acc[i] = fmaf(KOBS[(jg + 4 * i) * 64 + d], tv, acc[i]);
        }
#pragma unroll
        for (int i = 0; i < 8; ++i)
            kq[(b * 32 + (jg + 4 * i)) * 64 + h] = acc[i] * 0.125f;
    }
    if (t < 32) {
        float s = 0.f;
        for (int m = 0; m < 64; ++m) s = fmaf(qo2_b[m], KOBS[t * 64 + m], s);
        kb[b * 32 + t] = s * 0.125f;
    }
    __syncthreads();

    // ---- per-(b,j) bases/deltas ----
    float* SP = P; float* dAP = P + 2560;   // T dead
    for (int i = t; i < 2560; i += 256) {
        const int a_ = i / 80, k = i % 80;
        SP[i] = (k < 64) ? ST[a_ * 64 + k] : AP[512 + a_ * 16 + (k - 64)];
    }
    for (int i = t; i < 512; i += 256) dAP[i] = AP[i] - AP[512 + i];
    __syncthreads();

    layer256<80, false>(SP,  qo1_w,           qo1_b,  baseq  + b * 2048, h, jg);
    layer256<16, false>(dAP, qo1_w + 64 * 64, nullptr, deltaq + b * 2048, h, jg);

    float* BV = P + 4096;   // KOBS dead (synced above)
    layer256<80, false>(SP,  av1_w,           av1_b,  BV,               h, jg);
    layer256<16, false>(dAP, av1_w + 64 * 64, nullptr, deltav + b * 2048, h, jg);
    __syncthreads();

    for (int i = t; i < 2048; i += 256) {
        const float v = BV[i];
        basev[b * 2048 + i] = v;
        H[i] = v >= 0.f ? v : 0.01f * v;     // hpi = leaky(basev)
    }
    __syncthreads();

    layer256<64, false>(H,  M,     c,     vpf + b * 2048, h, jg);  // vals_pi@fv1b
    layer256<64, false>(ST, fv1_w, fv1_b, pre + b * 2048, h, jg);  // states@fv1a+fb1
}

// ---------------- kernel 2: per-(b,a) main ----------------
__global__ __launch_bounds__(256)
void main_kernel(const float* __restrict__ wz,     // B,N,N (from d_out)
                 const float* __restrict__ kq, const float* __restrict__ kb,
                 const float* __restrict__ baseq, const float* __restrict__ deltaq,
                 const float* __restrict__ basev, const float* __restrict__ deltav,
                 const float* __restrict__ pre,   const float* __restrict__ vpf,
                 const float* __restrict__ M,     const float* __restrict__ c,
                 const float* __restrict__ fv2_w, const float* __restrict__ fv2_b,
                 float* __restrict__ out_value,   // B,N,N
                 float* __restrict__ out_wobs)    // B,N,N
{
    const int bid0 = blockIdx.x;
    const int bid  = (bid0 & 7) * 512 + (bid0 >> 3);   // XCD swizzle (4096 = 8*512)
    const int b = bid >> 5, a = bid & 31;
    const int t = threadIdx.x, lane = t & 63, jg = t >> 6;

    __shared__ float s_hv[NN * HID];   // hv, then X = hbar - w_j*hv_j (in place)
    __shared__ float s_kq[HID], s_hbar[HID];
    __shared__ float s_sc[NN], s_w[NN], s_wzr[NN];
    __shared__ float s_kb;

    if (t < 32)                  s_wzr[t]     = wz[b * 1024 + a * 32 + t];
    else if (t >= 64 && t < 128) s_kq[t - 64] = kq[(b * 32 + a) * 64 + (t - 64)];
    else if (t == 128)           s_kb         = kb[b * 32 + a];
    __syncthreads();

    // scores: wave jg handles rows j = jg*8 .. jg*8+7
    {
        const float kqv = s_kq[lane];
#pragma unroll
        for (int i = 0; i < 8; ++i) {
            const int j = jg * 8 + i;
            const int rb = (b * 32 + j) * 64 + lane;
            float hq = baseq[rb] + s_wzr[j] * deltaq[rb];
            hq = hq >= 0.f ? hq : 0.01f * hq;
            float p = hq * kqv;
#pragma unroll
            for (int off = 32; off; off >>= 1) p += __shfl_xor(p, off);
            if (lane == 0) s_sc[j] = p + s_kb;
        }
    }
    __syncthreads();

    // softmax (t<32) — concurrent with hv build below
    if (t < 32) {
        float m = -1e30f;
        for (int j = 0; j < 32; ++j) m = fmaxf(m, s_sc[j]);
        float s = 0.f;
        for (int j = 0; j < 32; ++j) s += __expf(s_sc[j] - m);
        const float w = __expf(s_sc[t] - m) / s;
        s_w[t] = w;
        out_wobs[b * 1024 + a * 32 + t] = w;
    }
    // hv (all threads)
    for (int i = t; i < 2048; i += 256) {
        const int rb = b * 2048 + i;
        const float hv = basev[rb] + s_wzr[i >> 6] * deltav[rb];
        s_hv[i] = hv >= 0.f ? hv : 0.01f * hv;
    }
    __syncthreads();

    // hbar[d] = sum_j w[j]*hv[j][d]
    if (t < 64) {
        float acc = 0.f;
        for (int j = 0; j < 32; ++j) acc = fmaf(s_w[j], s_hv[j * 64 + t], acc);
        s_hbar[t] = acc;
    }
    __syncthreads();

    // X in place
    for (int i = t; i < 2048; i += 256)
        s_hv[i] = s_hbar[i & 63] - s_w[i >> 6] * s_hv[i];
    __syncthreads();

    // T = X @ M, then G = pre + (T + (1-w)c + w*vpf)/32, value = leaky(G).fv2 + fb2
    {
        float acc[8];
#pragma unroll
        for (int i = 0; i < 8; ++i) acc[i] = 0.f;
        for (int k = 0; k < 64; ++k) {
            const float mv = M[k * 64 + lane];
#pragma unroll
            for (int i = 0; i < 8; ++i)
                acc[i] = fmaf(s_hv[(jg + 4 * i) * 64 + k], mv, acc[i]);
        }
        const float ch  = c[lane];
        const float fvh = fv2_w[lane];
        const float fb2 = fv2_b[0];
#pragma unroll
        for (int i = 0; i < 8; ++i) {
            const int j = jg + 4 * i;
            const float wj = s_w[j];
            const int rb = (b * 32 + j) * 64 + lane;
            float g = pre[rb] + (acc[i] + (1.f - wj) * ch + wj * vpf[rb]) * (1.f / 32.f);
            g = g >= 0.f ? g : 0.01f * g;
            float p = g * fvh;
#pragma unroll
            for (int off = 32; off; off >>= 1) p += __shfl_xor(p, off);
            if (lane == 0) out_value[b * 1024 + a * 32 + j] = p + fb2;
        }
    }
}

extern "C" void kernel_launch(void* const* d_in, const int* in_sizes, int n_in,
                              void* d_out, int out_size, void* d_ws, size_t ws_size,
                              hipStream_t stream)
{
    const float* states   = (const float*)d_in[0];
    const float* policies = (const float*)d_in[1];
    const float* actions  = (const float*)d_in[2];
    const float* kw1_w = (const float*)d_in[3];  const float* kw1_b = (const float*)d_in[4];
    const float* kw2_w = (const float*)d_in[5];  const float* kw2_b = (const float*)d_in[6];
    const float* qw1_w = (const float*)d_in[7];  const float* qw1_b = (const float*)d_in[8];
    const float* qw2_w = (const float*)d_in[9];  const float* qw2_b = (const float*)d_in[10];
    const float* ko1_w = (const float*)d_in[11]; const float* ko1_b = (const float*)d_in[12];
    const float* ko2_w = (const float*)d_in[13]; const float* ko2_b = (const float*)d_in[14];
    const float* qo1_w = (const float*)d_in[15]; const float* qo1_b = (const float*)d_in[16];
    const float* qo2_w = (const float*)d_in[17]; const float* qo2_b = (const float*)d_in[18];
    const float* av1_w = (const float*)d_in[19]; const float* av1_b = (const float*)d_in[20];
    const float* av2_w = (const float*)d_in[21]; const float* av2_b = (const float*)d_in[22];
    const float* fv1_w = (const float*)d_in[23]; const float* fv1_b = (const float*)d_in[24];
    const float* fv2_w = (const float*)d_in[25]; const float* fv2_b = (const float*)d_in[26];

    float* out       = (float*)d_out;
    float* out_value = out;                 // B*N*N
    float* out_wz    = out + 131072;        // B*N*N
    float* out_wobs  = out + 262144;        // B*N*N

    float* ws    = (float*)d_ws;
    float* M_    = ws;                      // 4096
    float* c_    = ws + 4096;               // 64
    float* kb_   = ws + 4160;               // 4096
    float* kq_   = ws + 8256;               // 262144
    float* baseq = ws + 270400;             // 262144
    float* dq_   = ws + 532544;             // 262144
    float* basev = ws + 794688;             // 262144
    float* dv_   = ws + 1056832;            // 262144
    float* pre_  = ws + 1318976;            // 262144
    float* vpf_  = ws + 1581120;            // 262144  (end 1843264 floats = 7.0 MB)

    mm64_kernel<<<1, 256, 0, stream>>>(av2_w, av2_b, fv1_w, M_, c_);

    setup_kernel<<<NB, 256, 0, stream>>>(
        states, policies, actions,
        kw1_w, kw1_b, kw2_w, kw2_b,
        qw1_w, qw1_b, qw2_w, qw2_b,
        ko1_w, ko1_b, ko2_w, ko2_b,
        qo1_w, qo1_b, qo2_w, qo2_b,
        av1_w, av1_b, fv1_w, fv1_b,
        M_, c_,
        out_wz, kq_, kb_, baseq, dq_, basev, dv_, pre_, vpf_);

    main_kernel<<<NB * NN, 256, 0, stream>>>(
        out_wz, kq_, kb_, baseq, dq_, basev, dv_, pre_, vpf_,
        M_, c_, fv2_w, fv2_b,
        out_value, out_wobs);
}

// Round 5
// 107.861 us; speedup vs baseline: 2.7687x; 1.0583x over previous
//
#include <hip/hip_runtime.h>

#define NB   128
#define NN   32
#define OBS  64
#define ACTD 16
#define HID  64

__device__ __forceinline__ float leaky(float v) { return v >= 0.f ? v : 0.01f * v; }
__device__ __forceinline__ float wsum64(float p) {
#pragma unroll
    for (int off = 32; off; off >>= 1) p += __shfl_xor(p, off);
    return p;
}

// Per-wave 2-row layer: rows r0=jg, r1=jg+4 of the block's 8-row tile.
// Xl: LDS tile base (row stride K). O[r*64+h] = (ACT?leaky:id)(bias[h] + sum_k X[r][k]*W[k*64+h])
template<int K, bool ACT>
__device__ __forceinline__ void layer8(const float* Xl, const float* __restrict__ W,
                                       const float* __restrict__ bias,
                                       float* Ol, float* __restrict__ Og,
                                       int h, int jg)
{
    float a0 = bias ? bias[h] : 0.f;
    float a1 = a0;
    const float* x0 = Xl + jg * K;
    const float* x1 = Xl + (jg + 4) * K;
#pragma unroll 4
    for (int k = 0; k < K; ++k) {
        const float w = W[k * 64 + h];
        a0 = fmaf(x0[k], w, a0);
        a1 = fmaf(x1[k], w, a1);
    }
    if (ACT) { a0 = leaky(a0); a1 = leaky(a1); }
    if (Ol) { Ol[jg * 64 + h] = a0; Ol[(jg + 4) * 64 + h] = a1; }
    if (Og) { Og[jg * 64 + h] = a0; Og[(jg + 4) * 64 + h] = a1; }
}

// ---------------- kernel 0: M = av2_w @ fv1b, c = av2_b @ fv1b ----------------
__global__ __launch_bounds__(256)
void mm64_kernel(const float* __restrict__ av2_w, const float* __restrict__ av2_b,
                 const float* __restrict__ fv1_w,   // 128x64; rows 64..127 = fv1b
                 float* __restrict__ M, float* __restrict__ c)
{
    const int t = threadIdx.x, h = t & 63, jg = t >> 6;
    __shared__ float sA[64 * 64];
    for (int i = t; i < 4096; i += 256) sA[i] = av2_w[i];
    __syncthreads();
    const float* W = fv1_w + 64 * 64;
    float acc[16];
#pragma unroll
    for (int i = 0; i < 16; ++i) acc[i] = 0.f;
    for (int m = 0; m < 64; ++m) {
        const float w = W[m * 64 + h];
#pragma unroll
        for (int i = 0; i < 16; ++i)
            acc[i] = fmaf(sA[(jg + 4 * i) * 64 + m], w, acc[i]);
    }
#pragma unroll
    for (int i = 0; i < 16; ++i) M[(jg + 4 * i) * 64 + h] = acc[i];
    if (t < 64) {
        float s = 0.f;
        for (int m = 0; m < 64; ++m) s = fmaf(av2_b[m], W[m * 64 + t], s);
        c[t] = s;
    }
}

// ---------------- kernel 1: row-parallel setup (8 rows/block, 2 rows/wave) ----------------
__global__ __launch_bounds__(256)
void setup_kernel(const float* __restrict__ states,    // B,N,64
                  const float* __restrict__ policies,  // B,N,16
                  const float* __restrict__ actions,   // B,N,16
                  const float* __restrict__ kw1_w, const float* __restrict__ kw1_b,
                  const float* __restrict__ kw2_w, const float* __restrict__ kw2_b,
                  const float* __restrict__ qw1_w, const float* __restrict__ qw1_b,
                  const float* __restrict__ qw2_w, const float* __restrict__ qw2_b,
                  const float* __restrict__ ko1_w, const float* __restrict__ ko1_b,
                  const float* __restrict__ ko2_w, const float* __restrict__ ko2_b,
                  const float* __restrict__ qo1_w, const float* __restrict__ qo1_b,
                  const float* __restrict__ qo2_w, const float* __restrict__ qo2_b,
                  const float* __restrict__ av1_w, const float* __restrict__ av1_b,
                  const float* __restrict__ fv1_w, const float* __restrict__ fv1_b,
                  const float* __restrict__ M, const float* __restrict__ c,
                  float* __restrict__ kz,    float* __restrict__ qz,
                  float* __restrict__ kq,    float* __restrict__ kb,
                  float* __restrict__ baseq, float* __restrict__ deltaq,
                  float* __restrict__ basev, float* __restrict__ deltav,
                  float* __restrict__ pre,   float* __restrict__ vpf)
{
    const int blk = blockIdx.x;           // 512 blocks: (b, quarter)
    const int rowbase = blk * 8;          // global row index base (b*32 + q*8)
    const int t = threadIdx.x, h = t & 63, jg = t >> 6;

    __shared__ float sST[8 * 64];
    __shared__ float sACT[8 * 16], sPOL[8 * 16], sDAP[8 * 16];
    __shared__ float sH[8 * 64];
    __shared__ float sKZ[8 * 64], sQZ[8 * 64], sKOBS[8 * 64], sBV[8 * 64];
    __shared__ float sSRC[8 * 80];
    __shared__ float T[4096];             // qo2_w row-major, xor-swizzled cols

    for (int i = t; i < 512; i += 256) sST[i] = states[rowbase * 64 + i];
    for (int i = t; i < 128; i += 256) {
        const float av = actions [rowbase * 16 + i];
        const float pv = policies[rowbase * 16 + i];
        sACT[i] = av; sPOL[i] = pv; sDAP[i] = av - pv;
    }
    for (int i = t; i < 4096; i += 256) {
        const int hh = i >> 6, d = i & 63;
        T[hh * 64 + (d ^ (hh & 31))] = qo2_w[i];
    }
    __syncthreads();   // the only block-wide barrier

    // ---- kz, qz (per-wave rows jg, jg+4) ----
    layer8<64, true >(sST, kw1_w, kw1_b, sH,  nullptr,            h, jg);
    layer8<64, false>(sH,  kw2_w, kw2_b, sKZ, kz + rowbase * 64,  h, jg);
    layer8<64, true >(sST, qw1_w, qw1_b, sH,  nullptr,            h, jg);
    layer8<64, false>(sH,  qw2_w, qw2_b, sQZ, qz + rowbase * 64,  h, jg);

    // ---- wzd = sigmoid(kz.qz/8), broadcast in-register ----
    const float wzd0 = 1.f / (1.f + __expf(-wsum64(sKZ[jg * 64 + h] * sQZ[jg * 64 + h]) * 0.125f));
    const float wzd1 = 1.f / (1.f + __expf(-wsum64(sKZ[(jg + 4) * 64 + h] * sQZ[(jg + 4) * 64 + h]) * 0.125f));

    // ---- source rows [st, wzd*act + (1-wzd)*pol] ----
    sSRC[jg * 80 + h]       = sST[jg * 64 + h];
    sSRC[(jg + 4) * 80 + h] = sST[(jg + 4) * 64 + h];
    if (h < 16) {
        sSRC[jg * 80 + 64 + h]       = wzd0 * sACT[jg * 16 + h]       + (1.f - wzd0) * sPOL[jg * 16 + h];
        sSRC[(jg + 4) * 80 + 64 + h] = wzd1 * sACT[(jg + 4) * 16 + h] + (1.f - wzd1) * sPOL[(jg + 4) * 16 + h];
    }

    // ---- kobs ----
    layer8<80, true >(sSRC, ko1_w, ko1_b, sH,    nullptr, h, jg);
    layer8<64, false>(sH,   ko2_w, ko2_b, sKOBS, nullptr, h, jg);

    // ---- kq[h] = 0.125 * sum_d qo2_w[h][d]*kobs[d]; kb = 0.125 * qo2_b.kobs ----
    {
        float k0 = 0.f, k1 = 0.f;
#pragma unroll 4
        for (int d = 0; d < 64; ++d) {
            const float tv = T[h * 64 + (d ^ (h & 31))];
            k0 = fmaf(sKOBS[jg * 64 + d],       tv, k0);
            k1 = fmaf(sKOBS[(jg + 4) * 64 + d], tv, k1);
        }
        kq[(rowbase + jg) * 64 + h]     = k0 * 0.125f;
        kq[(rowbase + jg + 4) * 64 + h] = k1 * 0.125f;
        const float s0 = wsum64(qo2_b[h] * sKOBS[jg * 64 + h]);
        const float s1 = wsum64(qo2_b[h] * sKOBS[(jg + 4) * 64 + h]);
        if (h == 0) {
            kb[rowbase + jg]     = s0 * 0.125f;
            kb[rowbase + jg + 4] = s1 * 0.125f;
        }
    }

    // ---- SP rows [st, pol]: only cols 64..79 change ----
    if (h < 16) {
        sSRC[jg * 80 + 64 + h]       = sPOL[jg * 16 + h];
        sSRC[(jg + 4) * 80 + 64 + h] = sPOL[(jg + 4) * 16 + h];
    }

    layer8<80, false>(sSRC, qo1_w,          qo1_b,  nullptr, baseq  + rowbase * 64, h, jg);
    layer8<16, false>(sDAP, qo1_w + 4096,   nullptr, nullptr, deltaq + rowbase * 64, h, jg);
    layer8<80, false>(sSRC, av1_w,          av1_b,  sBV,     basev  + rowbase * 64, h, jg);
    layer8<16, false>(sDAP, av1_w + 4096,   nullptr, nullptr, deltav + rowbase * 64, h, jg);

    // ---- vpf = leaky(basev)@M + c ; pre = st@fv1a + fb1 ----
    sH[jg * 64 + h]       = leaky(sBV[jg * 64 + h]);
    sH[(jg + 4) * 64 + h] = leaky(sBV[(jg + 4) * 64 + h]);
    layer8<64, false>(sH,  M,     c,     nullptr, vpf + rowbase * 64, h, jg);
    layer8<64, false>(sST, fv1_w, fv1_b, nullptr, pre + rowbase * 64, h, jg);
}

// ---------------- kernel 2: per-(b,a) main ----------------
__global__ __launch_bounds__(256)
void main_kernel(const float* __restrict__ kz,    const float* __restrict__ qz,
                 const float* __restrict__ kq,    const float* __restrict__ kb,
                 const float* __restrict__ baseq, const float* __restrict__ deltaq,
                 const float* __restrict__ basev, const float* __restrict__ deltav,
                 const float* __restrict__ pre,   const float* __restrict__ vpf,
                 const float* __restrict__ M,     const float* __restrict__ c,
                 const float* __restrict__ fv2_w, const float* __restrict__ fv2_b,
                 float* __restrict__ out_value,   // B,N,N
                 float* __restrict__ out_wz,      // B,N,N
                 float* __restrict__ out_wobs)    // B,N,N
{
    const int bid0 = blockIdx.x;
    const int bid  = (bid0 & 7) * 512 + (bid0 >> 3);   // XCD swizzle (4096 = 8*512)
    const int b = bid >> 5, a = bid & 31;
    const int t = threadIdx.x, lane = t & 63, jg = t >> 6;

    __shared__ float pool[4096];       // QZ (2048) then M (4096)
    __shared__ float s_hv[NN * HID];   // hv, then X = hbar - w_j*hv_j (in place)
    __shared__ float s_hbar[HID];
    __shared__ float s_sc[NN], s_w[NN], s_wzr[NN];

    for (int i = t; i < 2048; i += 256) pool[i] = qz[b * 2048 + i];
    const float kzv = kz[(b * 32 + a) * 64 + lane];
    const float kqv = kq[(b * 32 + a) * 64 + lane];
    const float kbv = kb[b * 32 + a];
    __syncthreads();

    // weight_z row (own 8 j per wave) + write out_wz
#pragma unroll
    for (int i = 0; i < 8; ++i) {
        const int j = jg * 8 + i;
        const float p = wsum64(kzv * pool[j * 64 + lane]);
        const float w = 1.f / (1.f + __expf(-p * 0.125f));
        if (lane == 0) { s_wzr[j] = w; out_wz[b * 1024 + a * 32 + j] = w; }
    }
    // scores (uses own wave's s_wzr — wave-coherent)
#pragma unroll
    for (int i = 0; i < 8; ++i) {
        const int j = jg * 8 + i;
        const int rb = (b * 32 + j) * 64 + lane;
        const float hq = leaky(baseq[rb] + s_wzr[j] * deltaq[rb]);
        const float p = wsum64(hq * kqv);
        if (lane == 0) s_sc[j] = p + kbv;
    }
    __syncthreads();

    // softmax (t<32) ; hv build ; M stage (pool reuse — QZ dead)
    if (t < 32) {
        float m = -1e30f;
        for (int j = 0; j < 32; ++j) m = fmaxf(m, s_sc[j]);
        float s = 0.f;
        for (int j = 0; j < 32; ++j) s += __expf(s_sc[j] - m);
        const float w = __expf(s_sc[t] - m) / s;
        s_w[t] = w;
        out_wobs[b * 1024 + a * 32 + t] = w;
    }
    for (int i = t; i < 2048; i += 256) {
        const int rb = b * 2048 + i;
        s_hv[i] = leaky(basev[rb] + s_wzr[i >> 6] * deltav[rb]);
    }
    for (int i = t; i < 4096; i += 256) pool[i] = M[i];
    __syncthreads();

    // hbar[d] = sum_j w[j]*hv[j][d]
    if (t < 64) {
        float acc = 0.f;
        for (int j = 0; j < 32; ++j) acc = fmaf(s_w[j], s_hv[j * 64 + t], acc);
        s_hbar[t] = acc;
    }
    __syncthreads();

    // X in place
    for (int i = t; i < 2048; i += 256)
        s_hv[i] = s_hbar[i & 63] - s_w[i >> 6] * s_hv[i];
    __syncthreads();

    // T = X @ M (M from LDS), then G = pre + (T + (1-w)c + w*vpf)/32, value = leaky(G).fv2 + fb2
    {
        float acc[8];
#pragma unroll
        for (int i = 0; i < 8; ++i) acc[i] = 0.f;
#pragma unroll 4
        for (int k = 0; k < 64; ++k) {
            const float mv = pool[k * 64 + lane];
#pragma unroll
            for (int i = 0; i < 8; ++i)
                acc[i] = fmaf(s_hv[(jg + 4 * i) * 64 + k], mv, acc[i]);
        }
        const float ch  = c[lane];
        const float fvh = fv2_w[lane];
        const float fb2 = fv2_b[0];
#pragma unroll
        for (int i = 0; i < 8; ++i) {
            const int j = jg + 4 * i;
            const float wj = s_w[j];
            const int rb = (b * 32 + j) * 64 + lane;
            float g = pre[rb] + (acc[i] + (1.f - wj) * ch + wj * vpf[rb]) * (1.f / 32.f);
            g = leaky(g);
            const float p = wsum64(g * fvh);
            if (lane == 0) out_value[b * 1024 + a * 32 + j] = p + fb2;
        }
    }
}

extern "C" void kernel_launch(void* const* d_in, const int* in_sizes, int n_in,
                              void* d_out, int out_size, void* d_ws, size_t ws_size,
                              hipStream_t stream)
{
    const float* states   = (const float*)d_in[0];
    const float* policies = (const float*)d_in[1];
    const float* actions  = (const float*)d_in[2];
    const float* kw1_w = (const float*)d_in[3];  const float* kw1_b = (const float*)d_in[4];
    const float* kw2_w = (const float*)d_in[5];  const float* kw2_b = (const float*)d_in[6];
    const float* qw1_w = (const float*)d_in[7];  const float* qw1_b = (const float*)d_in[8];
    const float* qw2_w = (const float*)d_in[9];  const float* qw2_b = (const float*)d_in[10];
    const float* ko1_w = (const float*)d_in[11]; const float* ko1_b = (const float*)d_in[12];
    const float* ko2_w = (const float*)d_in[13]; const float* ko2_b = (const float*)d_in[14];
    const float* qo1_w = (const float*)d_in[15]; const float* qo1_b = (const float*)d_in[16];
    const float* qo2_w = (const float*)d_in[17]; const float* qo2_b = (const float*)d_in[18];
    const float* av1_w = (const float*)d_in[19]; const float* av1_b = (const float*)d_in[20];
    const float* av2_w = (const float*)d_in[21]; const float* av2_b = (const float*)d_in[22];
    const float* fv1_w = (const float*)d_in[23]; const float* fv1_b = (const float*)d_in[24];
    const float* fv2_w = (const float*)d_in[25]; const float* fv2_b = (const float*)d_in[26];

    float* out       = (float*)d_out;
    float* out_value = out;                 // B*N*N
    float* out_wz    = out + 131072;        // B*N*N
    float* out_wobs  = out + 262144;        // B*N*N

    const int SZ = 262144;                  // B*N*64
    float* ws    = (float*)d_ws;
    float* M_    = ws;                      // 4096
    float* c_    = ws + 4096;               // 64
    float* kb_   = ws + 4160;               // 4096
    float* kz_   = ws + 8256;
    float* qz_   = kz_   + SZ;
    float* kq_   = qz_   + SZ;
    float* baseq = kq_   + SZ;
    float* dq_   = baseq + SZ;
    float* basev = dq_   + SZ;
    float* dv_   = basev + SZ;
    float* pre_  = dv_   + SZ;
    float* vpf_  = pre_  + SZ;              // end: 8256 + 9*262144 floats ≈ 9.5 MB

    mm64_kernel<<<1, 256, 0, stream>>>(av2_w, av2_b, fv1_w, M_, c_);

    setup_kernel<<<NB * 4, 256, 0, stream>>>(
        states, policies, actions,
        kw1_w, kw1_b, kw2_w, kw2_b,
        qw1_w, qw1_b, qw2_w, qw2_b,
        ko1_w, ko1_b, ko2_w, ko2_b,
        qo1_w, qo1_b, qo2_w, qo2_b,
        av1_w, av1_b, fv1_w, fv1_b,
        M_, c_,
        kz_, qz_, kq_, kb_, baseq, dq_, basev, dv_, pre_, vpf_);

    main_kernel<<<NB * NN, 256, 0, stream>>>(
        kz_, qz_, kq_, kb_, baseq, dq_, basev, dv_, pre_, vpf_,
        M_, c_, fv2_w, fv2_b,
        out_value, out_wz, out_wobs);
}